// Round 1
// baseline (290.331 us; speedup 1.0000x reference)
//
#include <hip/hip_runtime.h>

// RBF kernel: out[i,j] = exp(-||x_i - y_j||^2), x,y: [8192,256] fp32, out fp32.
// Strategy: dist2 = x2[i] + y2[j] - 2*(x.y); x.y via bf16 MFMA (m97-style GEMM),
// norms in fp32. exp underflows to 0 for dist2 > ~104 (typical here ~512), so
// bf16 rounding of the cross term is numerically irrelevant.

#define M_DIM 8192
#define K_DIM 256
#define BM 128
#define BN 128
#define BK 64

typedef __attribute__((ext_vector_type(8))) short short8;
typedef __attribute__((ext_vector_type(4))) float float4v;

__device__ inline unsigned short f2bf(float f) {
    union { float f; unsigned int u; } a; a.f = f;
    unsigned int u = a.u;
    unsigned int r = u + 0x7fffu + ((u >> 16) & 1u);   // RNE
    return (unsigned short)(r >> 16);
}

// One wave per row: convert 256 fp32 -> 256 bf16 and compute fp32 sum of squares.
__global__ __launch_bounds__(256) void prep_kernel(
        const float* __restrict__ x, const float* __restrict__ y,
        unsigned short* __restrict__ xb, unsigned short* __restrict__ yb,
        float* __restrict__ x2, float* __restrict__ y2) {
    int row  = blockIdx.x * 4 + (threadIdx.x >> 6);   // 4 waves/block
    int lane = threadIdx.x & 63;

    const float* src; unsigned short* dst; float* nrm; int r;
    if (row < M_DIM) { src = x; dst = xb; nrm = x2; r = row; }
    else             { src = y; dst = yb; nrm = y2; r = row - M_DIM; }

    const float4* s4 = (const float4*)(src + (size_t)r * K_DIM);
    float4 v = s4[lane];
    float ss = v.x * v.x + v.y * v.y + v.z * v.z + v.w * v.w;

    ushort4 p;
    p.x = f2bf(v.x); p.y = f2bf(v.y); p.z = f2bf(v.z); p.w = f2bf(v.w);
    ((ushort4*)(dst + (size_t)r * K_DIM))[lane] = p;

    #pragma unroll
    for (int o = 32; o > 0; o >>= 1) ss += __shfl_down(ss, o);
    if (lane == 0) nrm[r] = ss;
}

// 128x128 block tile, 4 waves in 2x2, each wave 4x4 tiles of 16x16x32 bf16 MFMA.
__global__ __launch_bounds__(256, 2) void rbf_gemm(
        const unsigned short* __restrict__ xb, const unsigned short* __restrict__ yb,
        const float* __restrict__ x2, const float* __restrict__ y2,
        float* __restrict__ out) {
    __shared__ __align__(16) unsigned short As[BM * BK];
    __shared__ __align__(16) unsigned short Bs[BN * BK];

    const int tid  = threadIdx.x;
    const int wid  = tid >> 6;
    const int lane = tid & 63;
    const int wm   = wid >> 1;        // 0..1
    const int wn   = wid & 1;         // 0..1
    const int m0   = blockIdx.y * BM;
    const int n0   = blockIdx.x * BN;

    float4v acc[4][4] = {};

    const int lrow8 = lane >> 3;      // 0..7  (row within 8-row group)
    const int lchk  = lane & 7;       // 16B chunk within a 128B row

    for (int kt = 0; kt < K_DIM; kt += BK) {
        // Stage A: 128x64 bf16 (16KB). Each issue: wave stages 8 rows (1KB).
        #pragma unroll
        for (int i = 0; i < 4; ++i) {
            int rbase = i * 32 + wid * 8;
            const unsigned short* ga = xb
                + (size_t)(m0 + rbase + lrow8) * K_DIM + kt + lchk * 8;
            __builtin_amdgcn_global_load_lds(
                (__attribute__((address_space(1))) void*)ga,
                (__attribute__((address_space(3))) void*)&As[rbase * BK],
                16, 0, 0);
        }
        // Stage B: 128x64 bf16.
        #pragma unroll
        for (int i = 0; i < 4; ++i) {
            int rbase = i * 32 + wid * 8;
            const unsigned short* gb = yb
                + (size_t)(n0 + rbase + lrow8) * K_DIM + kt + lchk * 8;
            __builtin_amdgcn_global_load_lds(
                (__attribute__((address_space(1))) void*)gb,
                (__attribute__((address_space(3))) void*)&Bs[rbase * BK],
                16, 0, 0);
        }
        __syncthreads();   // emits s_waitcnt vmcnt(0) before s_barrier

        #pragma unroll
        for (int ks = 0; ks < 2; ++ks) {
            const int colk = ks * 32 + (lane >> 4) * 8;
            short8 af[4], bfr[4];
            #pragma unroll
            for (int mt = 0; mt < 4; ++mt)
                af[mt] = *(const short8*)&As[(wm * 64 + mt * 16 + (lane & 15)) * BK + colk];
            #pragma unroll
            for (int nt = 0; nt < 4; ++nt)
                bfr[nt] = *(const short8*)&Bs[(wn * 64 + nt * 16 + (lane & 15)) * BK + colk];
            #pragma unroll
            for (int mt = 0; mt < 4; ++mt)
                #pragma unroll
                for (int nt = 0; nt < 4; ++nt)
                    acc[mt][nt] = __builtin_amdgcn_mfma_f32_16x16x32_bf16(
                        af[mt], bfr[nt], acc[mt][nt], 0, 0, 0);
        }
        __syncthreads();
    }

    // Epilogue: dist2 = x2 + y2 - 2*s ; out = exp(-max(dist2,0))
    const int q = lane >> 4;          // 0..3
    const int c = lane & 15;
    #pragma unroll
    for (int mt = 0; mt < 4; ++mt) {
        const int rowb = m0 + wm * 64 + mt * 16 + q * 4;
        float x2v[4];
        #pragma unroll
        for (int v = 0; v < 4; ++v) x2v[v] = x2[rowb + v];
        #pragma unroll
        for (int nt = 0; nt < 4; ++nt) {
            const int col = n0 + wn * 64 + nt * 16 + c;
            const float y2v = y2[col];
            #pragma unroll
            for (int v = 0; v < 4; ++v) {
                float d = x2v[v] + y2v - 2.0f * acc[mt][nt][v];
                d = fmaxf(d, 0.0f);
                out[(size_t)(rowb + v) * M_DIM + col] = __expf(-d);
            }
        }
    }
}

// Fallback if workspace is too small: fp32 tiled direct distance.
__global__ void rbf_naive(const float* __restrict__ x, const float* __restrict__ y,
                          float* __restrict__ out) {
    __shared__ float xs[16][17];
    __shared__ float ys[16][17];
    const int tx = threadIdx.x, ty = threadIdx.y;
    const int row = blockIdx.y * 16 + ty;
    const int col = blockIdx.x * 16 + tx;
    float acc = 0.0f;
    for (int k0 = 0; k0 < K_DIM; k0 += 16) {
        xs[ty][tx] = x[(size_t)row * K_DIM + k0 + tx];
        ys[ty][tx] = y[(size_t)(blockIdx.x * 16 + ty) * K_DIM + k0 + tx];
        __syncthreads();
        #pragma unroll
        for (int kk = 0; kk < 16; ++kk) {
            float d = xs[ty][kk] - ys[tx][kk];
            acc += d * d;
        }
        __syncthreads();
    }
    out[(size_t)row * M_DIM + col] = __expf(-acc);
}

extern "C" void kernel_launch(void* const* d_in, const int* in_sizes, int n_in,
                              void* d_out, int out_size, void* d_ws, size_t ws_size,
                              hipStream_t stream) {
    const float* x = (const float*)d_in[0];
    const float* y = (const float*)d_in[1];
    float* out = (float*)d_out;

    const size_t need = (size_t)2 * M_DIM * K_DIM * sizeof(unsigned short)
                      + (size_t)2 * M_DIM * sizeof(float);
    if (ws_size >= need) {
        unsigned short* xb = (unsigned short*)d_ws;
        unsigned short* yb = xb + (size_t)M_DIM * K_DIM;
        float* x2 = (float*)(yb + (size_t)M_DIM * K_DIM);
        float* y2 = x2 + M_DIM;

        prep_kernel<<<dim3((2 * M_DIM) / 4), dim3(256), 0, stream>>>(x, y, xb, yb, x2, y2);
        rbf_gemm<<<dim3(M_DIM / BN, M_DIM / BM), dim3(256), 0, stream>>>(xb, yb, x2, y2, out);
    } else {
        rbf_naive<<<dim3(M_DIM / 16, M_DIM / 16), dim3(16, 16), 0, stream>>>(x, y, out);
    }
}